// Round 1
// baseline (117.208 us; speedup 1.0000x reference)
//
#include <hip/hip_runtime.h>

// PointSpatialTransformer: bilinear gather of normalized-flow field at 4M points.
// H = W = 512, L table = 512*512 float2 = 2 MB (fits per-XCD L2).

constexpr int HH = 512;
constexpr int WW = 512;

// ---------------- Kernel 1: build L table (float2 interleaved) ----------------
// L[i][j].x = (j + flow[1][i][j]) * 2/511 - 1
// L[i][j].y = (i + flow[0][i][j]) * 2/511 - 1
__global__ __launch_bounds__(256) void build_L_kernel(const float* __restrict__ flow,
                                                      float2* __restrict__ L) {
    int idx = blockIdx.x * 256 + threadIdx.x;   // 0 .. 262143
    int i = idx >> 9;          // row (H)
    int j = idx & 511;         // col (W)
    float f0 = flow[idx];               // channel 0
    float f1 = flow[idx + HH * WW];     // channel 1
    const float s = 2.0f / 511.0f;
    L[idx] = make_float2(fmaf((float)j + f1, s, -1.0f),
                         fmaf((float)i + f0, s, -1.0f));
}

// ---------------- L lookup (table or flow-direct fallback) ----------------
template <bool USE_TABLE>
__device__ __forceinline__ float2 load_L(const float2* __restrict__ L,
                                         const float* __restrict__ flow,
                                         int x, int y) {
    int idx = (x << 9) + y;
    if constexpr (USE_TABLE) {
        return L[idx];
    } else {
        float f0 = flow[idx];
        float f1 = flow[idx + HH * WW];
        const float s = 2.0f / 511.0f;
        return make_float2(fmaf((float)y + f1, s, -1.0f),
                           fmaf((float)x + f0, s, -1.0f));
    }
}

template <bool USE_TABLE>
__device__ __forceinline__ float2 process_point(float x, float y, bool bil,
                                                const float2* __restrict__ L,
                                                const float* __restrict__ flow) {
    float2 tmp;
    if (bil) {
        float xt = truncf(x), yt = truncf(y);
        float xf = x - xt, yf = y - yt;
        int x0 = (int)xt, y0 = (int)yt;
        // v00=L[x0,y0] v01=L[x0,y1] v10=L[x1,y0] v11=L[x1,y1]
        float2 v00 = load_L<USE_TABLE>(L, flow, x0,     y0);
        float2 v01 = load_L<USE_TABLE>(L, flow, x0,     y0 + 1);
        float2 v10 = load_L<USE_TABLE>(L, flow, x0 + 1, y0);
        float2 v11 = load_L<USE_TABLE>(L, flow, x0 + 1, y0 + 1);
        float w00 = xf * yf;
        float w10 = xf * (1.0f - yf);
        float w01 = (1.0f - xf) * yf;
        float w11 = (1.0f - xf) * (1.0f - yf);
        tmp.x = w00 * v00.x + w10 * v10.x + w01 * v01.x + w11 * v11.x;
        tmp.y = w00 * v00.y + w10 * v10.y + w01 * v01.y + w11 * v11.y;
    } else {
        int xi = min((int)rintf(x), 511);
        int yi = min((int)rintf(y), 511);
        tmp = load_L<USE_TABLE>(L, flow, xi, yi);
    }
    // out0 = (tmp.y + 1)/2*512 ; out1 = (tmp.x + 1)/2*512 ; stored as (out0, out1)
    return make_float2((tmp.y + 1.0f) * 256.0f,
                       (tmp.x + 1.0f) * 256.0f);
}

// ---------------- Kernel 2: gather + interpolate, 2 points/thread ----------------
template <bool USE_TABLE>
__global__ __launch_bounds__(256) void pst_kernel(const float* __restrict__ point,
                                                  const float2* __restrict__ L,
                                                  const float* __restrict__ flow,
                                                  const int* __restrict__ intep,
                                                  float* __restrict__ out,
                                                  int n /* number of points */) {
    const bool bil = (*intep != 0);
    const int npairs = n >> 1;
    int tid = blockIdx.x * blockDim.x + threadIdx.x;
    int stride = gridDim.x * blockDim.x;

    const float4* pts4 = reinterpret_cast<const float4*>(point);
    float4* out4 = reinterpret_cast<float4*>(out);

    for (int i = tid; i < npairs; i += stride) {
        float4 p = pts4[i];   // two points: (x0,y0,x1,y1)
        float2 r0 = process_point<USE_TABLE>(p.x, p.y, bil, L, flow);
        float2 r1 = process_point<USE_TABLE>(p.z, p.w, bil, L, flow);
        out4[i] = make_float4(r0.x, r0.y, r1.x, r1.y);
    }
    // odd tail (n is 4M in practice, but stay correct)
    if ((n & 1) && tid == 0) {
        const float2* pt2 = reinterpret_cast<const float2*>(point);
        float2 p = pt2[n - 1];
        float2 r = process_point<USE_TABLE>(p.x, p.y, bil, L, flow);
        reinterpret_cast<float2*>(out)[n - 1] = r;
    }
}

extern "C" void kernel_launch(void* const* d_in, const int* in_sizes, int n_in,
                              void* d_out, int out_size, void* d_ws, size_t ws_size,
                              hipStream_t stream) {
    const float* point = (const float*)d_in[0];  // (1, N, 2)
    const float* flow  = (const float*)d_in[1];  // (1, 2, 512, 512)
    const int*   intep = (const int*)d_in[2];    // scalar
    float* out = (float*)d_out;                  // (1, N, 2)

    const int n = in_sizes[0] / 2;               // number of points
    const int npairs = n >> 1;

    const size_t table_bytes = (size_t)HH * WW * sizeof(float2); // 2 MB
    const bool use_table = (ws_size >= table_bytes);

    int blocks = (npairs + 255) / 256;
    if (blocks > 2048) blocks = 2048;            // grid-stride the rest
    if (blocks < 1) blocks = 1;

    if (use_table) {
        float2* L = (float2*)d_ws;
        build_L_kernel<<<HH * WW / 256, 256, 0, stream>>>(flow, L);
        pst_kernel<true><<<blocks, 256, 0, stream>>>(point, L, flow, intep, out, n);
    } else {
        pst_kernel<false><<<blocks, 256, 0, stream>>>(point, nullptr, flow, intep, out, n);
    }
}

// Round 4
// 114.880 us; speedup vs baseline: 1.0203x; 1.0203x over previous
//
#include <hip/hip_runtime.h>
#include <hip/hip_fp16.h>

// PointSpatialTransformer: bilinear gather of normalized-flow field at 4M points.
// H = W = 512.
// Strategy: precompute a 4 MB "quad table" T[512][512] (uint4), where each entry
// packs the FOUR bilinear corners of cell (i,j) as 4 x half2:
//   e.x = half2(Lx[i][j],     Ly[i][j])      // v00
//   e.y = half2(Lx[i][j+1],   Ly[i][j+1])    // v01
//   e.z = half2(Lx[i+1][j],   Ly[i+1][j])    // v10
//   e.w = half2(Lx[i+1][j+1], Ly[i+1][j+1])  // v11
// -> ONE 16B gather per point instead of four 8B gathers (request-bound kernel).
// fp16 quantization of L in [-1,1] adds <=5e-4 abs error -> <=0.13 in the output,
// far under the 10.24 threshold.

constexpr int HH = 512;
constexpr int WW = 512;

// clang native vector for nontemporal builtins (HIP_vector_type is rejected)
typedef float f32x4 __attribute__((ext_vector_type(4)));

__device__ __forceinline__ float Lx_val(const float* __restrict__ flow, int i, int j) {
    // Lx = (j + flow[1][i][j]) * 2/511 - 1
    const float s = 2.0f / 511.0f;
    return fmaf((float)j + flow[(i << 9) + j + HH * WW], s, -1.0f);
}
__device__ __forceinline__ float Ly_val(const float* __restrict__ flow, int i, int j) {
    // Ly = (i + flow[0][i][j]) * 2/511 - 1
    const float s = 2.0f / 511.0f;
    return fmaf((float)i + flow[(i << 9) + j], s, -1.0f);
}

__device__ __forceinline__ unsigned int pack_corner(const float* __restrict__ flow,
                                                    int i, int j) {
    __half2 h = __float22half2_rn(make_float2(Lx_val(flow, i, j), Ly_val(flow, i, j)));
    return *reinterpret_cast<unsigned int*>(&h);
}

// ---------------- Kernel 1: build quad table ----------------
__global__ __launch_bounds__(256) void build_T_kernel(const float* __restrict__ flow,
                                                      uint4* __restrict__ T) {
    int idx = blockIdx.x * 256 + threadIdx.x;   // 0 .. 262143
    int i = idx >> 9;
    int j = idx & 511;
    int ip = min(i + 1, 511);
    int jp = min(j + 1, 511);
    uint4 e;
    e.x = pack_corner(flow, i,  j);
    e.y = pack_corner(flow, i,  jp);
    e.z = pack_corner(flow, ip, j);
    e.w = pack_corner(flow, ip, jp);
    T[idx] = e;
}

__device__ __forceinline__ float2 h2f(unsigned int u) {
    __half2 h = *reinterpret_cast<__half2*>(&u);
    float2 f = __half22float2(h);
    return f;
}

// ---------------- per-point processing ----------------
__device__ __forceinline__ float2 process_point_tbl(float x, float y, bool bil,
                                                    const uint4* __restrict__ T) {
    float2 tmp;
    if (bil) {
        float xt = truncf(x), yt = truncf(y);
        float xf = x - xt, yf = y - yt;
        int x0 = (int)xt, y0 = (int)yt;
        uint4 e = T[(x0 << 9) + y0];   // single 16B gather: all 4 corners
        float2 v00 = h2f(e.x);
        float2 v01 = h2f(e.y);
        float2 v10 = h2f(e.z);
        float2 v11 = h2f(e.w);
        float w00 = xf * yf;
        float w10 = xf * (1.0f - yf);
        float w01 = (1.0f - xf) * yf;
        float w11 = (1.0f - xf) * (1.0f - yf);
        tmp.x = w00 * v00.x + w10 * v10.x + w01 * v01.x + w11 * v11.x;
        tmp.y = w00 * v00.y + w10 * v10.y + w01 * v01.y + w11 * v11.y;
    } else {
        int xi = min((int)rintf(x), 511);
        int yi = min((int)rintf(y), 511);
        uint4 e = T[(xi << 9) + yi];
        tmp = h2f(e.x);
    }
    // out0 = (tmp.y + 1)*256 ; out1 = (tmp.x + 1)*256 ; stored as (out0, out1)
    return make_float2((tmp.y + 1.0f) * 256.0f,
                       (tmp.x + 1.0f) * 256.0f);
}

// fallback (no workspace): recompute L from flow per corner, fp32 exact
__device__ __forceinline__ float2 load_L_direct(const float* __restrict__ flow,
                                                int x, int y) {
    return make_float2(Lx_val(flow, x, y), Ly_val(flow, x, y));
}

__device__ __forceinline__ float2 process_point_direct(float x, float y, bool bil,
                                                       const float* __restrict__ flow) {
    float2 tmp;
    if (bil) {
        float xt = truncf(x), yt = truncf(y);
        float xf = x - xt, yf = y - yt;
        int x0 = (int)xt, y0 = (int)yt;
        float2 v00 = load_L_direct(flow, x0,     y0);
        float2 v01 = load_L_direct(flow, x0,     y0 + 1);
        float2 v10 = load_L_direct(flow, x0 + 1, y0);
        float2 v11 = load_L_direct(flow, x0 + 1, y0 + 1);
        float w00 = xf * yf;
        float w10 = xf * (1.0f - yf);
        float w01 = (1.0f - xf) * yf;
        float w11 = (1.0f - xf) * (1.0f - yf);
        tmp.x = w00 * v00.x + w10 * v10.x + w01 * v01.x + w11 * v11.x;
        tmp.y = w00 * v00.y + w10 * v10.y + w01 * v01.y + w11 * v11.y;
    } else {
        int xi = min((int)rintf(x), 511);
        int yi = min((int)rintf(y), 511);
        tmp = load_L_direct(flow, xi, yi);
    }
    return make_float2((tmp.y + 1.0f) * 256.0f,
                       (tmp.x + 1.0f) * 256.0f);
}

// ---------------- Kernel 2: gather + interpolate, 2 points/thread ----------------
template <bool USE_TABLE>
__global__ __launch_bounds__(256) void pst_kernel(const float* __restrict__ point,
                                                  const uint4* __restrict__ T,
                                                  const float* __restrict__ flow,
                                                  const int* __restrict__ intep,
                                                  float* __restrict__ out,
                                                  int n /* number of points */) {
    const bool bil = (*intep != 0);
    const int npairs = n >> 1;
    int tid = blockIdx.x * blockDim.x + threadIdx.x;
    int stride = gridDim.x * blockDim.x;

    const f32x4* pts4 = reinterpret_cast<const f32x4*>(point);
    f32x4* out4 = reinterpret_cast<f32x4*>(out);

    for (int i = tid; i < npairs; i += stride) {
        // nontemporal: pure streaming, keep L2 for the table
        f32x4 p = __builtin_nontemporal_load(&pts4[i]);
        float2 r0, r1;
        if constexpr (USE_TABLE) {
            r0 = process_point_tbl(p.x, p.y, bil, T);
            r1 = process_point_tbl(p.z, p.w, bil, T);
        } else {
            r0 = process_point_direct(p.x, p.y, bil, flow);
            r1 = process_point_direct(p.z, p.w, bil, flow);
        }
        f32x4 r = {r0.x, r0.y, r1.x, r1.y};
        __builtin_nontemporal_store(r, &out4[i]);
    }
    if ((n & 1) && tid == 0) {
        const float2* pt2 = reinterpret_cast<const float2*>(point);
        float2 p = pt2[n - 1];
        float2 r;
        if constexpr (USE_TABLE) r = process_point_tbl(p.x, p.y, bil, T);
        else                     r = process_point_direct(p.x, p.y, bil, flow);
        reinterpret_cast<float2*>(out)[n - 1] = r;
    }
}

extern "C" void kernel_launch(void* const* d_in, const int* in_sizes, int n_in,
                              void* d_out, int out_size, void* d_ws, size_t ws_size,
                              hipStream_t stream) {
    const float* point = (const float*)d_in[0];  // (1, N, 2)
    const float* flow  = (const float*)d_in[1];  // (1, 2, 512, 512)
    const int*   intep = (const int*)d_in[2];    // scalar
    float* out = (float*)d_out;                  // (1, N, 2)

    const int n = in_sizes[0] / 2;               // number of points
    const int npairs = n >> 1;

    const size_t table_bytes = (size_t)HH * WW * sizeof(uint4); // 4 MB
    const bool use_table = (ws_size >= table_bytes);

    int blocks = (npairs + 255) / 256;
    if (blocks > 2048) blocks = 2048;            // grid-stride the rest
    if (blocks < 1) blocks = 1;

    if (use_table) {
        uint4* T = (uint4*)d_ws;
        build_T_kernel<<<HH * WW / 256, 256, 0, stream>>>(flow, T);
        pst_kernel<true><<<blocks, 256, 0, stream>>>(point, T, flow, intep, out, n);
    } else {
        pst_kernel<false><<<blocks, 256, 0, stream>>>(point, nullptr, flow, intep, out, n);
    }
}